// Round 1
// baseline (500.600 us; speedup 1.0000x reference)
//
#include <hip/hip_runtime.h>

typedef __bf16 bf16;
typedef __bf16 bf16x8 __attribute__((ext_vector_type(8)));
typedef float  floatx4 __attribute__((ext_vector_type(4)));

#define MFMA(a, b, c) __builtin_amdgcn_mfma_f32_16x16x32_bf16((a), (b), (c), 0, 0, 0)

static constexpr int S_LEN = 4096;
static constexpr int DMODEL = 768;
static constexpr int NHEAD = 12;
static constexpr int DKH = 64;

// ---------------------------------------------------------------------------
// GEMM: C[M,N] = A[M,K] @ B[K,N] + bias[N]
// A is fp32 or bf16 (A_BF16), B/bias fp32, C out fp32 or bf16 (OUT_BF16).
// 64x64 tile per 256-thread block (4 waves), BK=32, mfma_f32_16x16x32_bf16.
// Wave w computes rows [w*16, w*16+16), all 64 cols (4 col-tiles of 16).
// ---------------------------------------------------------------------------
template <bool OUT_BF16, bool A_BF16>
__global__ __launch_bounds__(256) void gemm_bias_kernel(
    const void* __restrict__ Av, const float* __restrict__ B,
    const float* __restrict__ bias, void* __restrict__ Cv,
    int M, int N, int K)
{
    constexpr int LDA = 40;  // bf16 elems: 32 + 8 pad (80 B, 16B-aligned rows)
    constexpr int LDB = 40;
    __shared__ bf16 As[64 * LDA];        // [m][k]
    __shared__ bf16 Bs[64 * LDB];        // transposed: [n][k]

    const int tid  = threadIdx.x;
    const int wave = tid >> 6;
    const int lane = tid & 63;
    const int quad = lane >> 4;
    const int l16  = lane & 15;
    const int m0 = blockIdx.x * 64;
    const int n0 = blockIdx.y * 64;

    floatx4 acc[4] = {};

    for (int k0 = 0; k0 < K; k0 += 32) {
        // stage A tile 64x32 (coalesced: 32 consecutive k per row)
#pragma unroll
        for (int i = 0; i < 8; ++i) {
            int idx = i * 256 + tid;           // 0..2047
            int m = idx >> 5, kk = idx & 31;
            bf16 aval;
            if (A_BF16) aval = ((const bf16*)Av)[(m0 + m) * K + k0 + kk];
            else        aval = (bf16)(((const float*)Av)[(m0 + m) * K + k0 + kk]);
            As[m * LDA + kk] = aval;
        }
        // stage B tile 32x64, store transposed [n][k]
#pragma unroll
        for (int i = 0; i < 8; ++i) {
            int idx = i * 256 + tid;
            int kk = idx >> 6, n = idx & 63;
            Bs[n * LDB + kk] = (bf16)B[(k0 + kk) * N + n0 + n];
        }
        __syncthreads();

        bf16x8 a = *(const bf16x8*)&As[(wave * 16 + l16) * LDA + quad * 8];
#pragma unroll
        for (int ct = 0; ct < 4; ++ct) {
            bf16x8 b = *(const bf16x8*)&Bs[(ct * 16 + l16) * LDB + quad * 8];
            acc[ct] = MFMA(a, b, acc[ct]);
        }
        __syncthreads();
    }

    // epilogue: C row = m0 + wave*16 + quad*4 + r, col = n0 + ct*16 + l16
    const int row = m0 + wave * 16 + quad * 4;
#pragma unroll
    for (int ct = 0; ct < 4; ++ct) {
        int col = n0 + ct * 16 + l16;
        float bv = bias[col];
#pragma unroll
        for (int r = 0; r < 4; ++r) {
            float v = acc[ct][r] + bv;
            if (OUT_BF16) ((bf16*)Cv)[(row + r) * N + col] = (bf16)v;
            else          ((float*)Cv)[(row + r) * N + col] = v;
        }
    }
}

// ---------------------------------------------------------------------------
// Causal flash attention, one block per (q-block of 64 rows, head).
// Q,K,V bf16 in [S, DMODEL] layout (head h at cols h*64..h*64+64).
// Online softmax; P re-enters MFMA A-layout via LDS round-trip.
// ---------------------------------------------------------------------------
__global__ __launch_bounds__(256) void attn_kernel(
    const bf16* __restrict__ Q, const bf16* __restrict__ K,
    const bf16* __restrict__ V, bf16* __restrict__ X)
{
    constexpr int LD = 72;  // 64 + 8 pad (144 B rows, 16B-aligned)
    __shared__ bf16 Qs[64 * LD];  // [q][dk]
    __shared__ bf16 Ks[64 * LD];  // [key][dk]  (natural: serves as B=K^T)
    __shared__ bf16 Vt[64 * LD];  // [dk][key]  (transposed V)
    __shared__ bf16 Ps[64 * LD];  // [q][key]

    const int h  = blockIdx.y;
    const int qb = (int)gridDim.x - 1 - (int)blockIdx.x;  // heavy blocks first
    const int tid  = threadIdx.x;
    const int wave = tid >> 6;
    const int lane = tid & 63;
    const int quad = lane >> 4;
    const int l16  = lane & 15;
    const int cbase = h * DKH;

    // load Q tile (64 x 64)
#pragma unroll
    for (int i = 0; i < 16; ++i) {
        int idx = i * 256 + tid;
        int r = idx >> 6, c = idx & 63;
        Qs[r * LD + c] = Q[(qb * 64 + r) * DMODEL + cbase + c];
    }

    floatx4 o[4] = {};
    float m_i[4], l_i[4];
#pragma unroll
    for (int r = 0; r < 4; ++r) { m_i[r] = -1e30f; l_i[r] = 0.0f; }

    for (int j = 0; j <= qb; ++j) {
        // stage K tile (natural) and V tile (transposed)
#pragma unroll
        for (int i = 0; i < 16; ++i) {
            int idx = i * 256 + tid;
            int r = idx >> 6, c = idx & 63;
            const int gk = (j * 64 + r) * DMODEL + cbase + c;
            Ks[r * LD + c] = K[gk];
            Vt[c * LD + r] = V[gk];
        }
        __syncthreads();

        // S = Q @ K^T  (wave rows wave*16..+16, cols = 64 keys)
        floatx4 s[4] = {};
#pragma unroll
        for (int ks = 0; ks < 2; ++ks) {
            bf16x8 a = *(const bf16x8*)&Qs[(wave * 16 + l16) * LD + ks * 32 + quad * 8];
#pragma unroll
            for (int ct = 0; ct < 4; ++ct) {
                bf16x8 b = *(const bf16x8*)&Ks[(ct * 16 + l16) * LD + ks * 32 + quad * 8];
                s[ct] = MFMA(a, b, s[ct]);
            }
        }

        // scale + causal mask + online softmax (row = wave*16 + quad*4 + r)
#pragma unroll
        for (int r = 0; r < 4; ++r) {
            const int qi = qb * 64 + wave * 16 + quad * 4 + r;
            float mx = -1e30f;
#pragma unroll
            for (int ct = 0; ct < 4; ++ct) {
                float sv = s[ct][r] * 0.125f;            // 1/sqrt(64)
                int kj = j * 64 + ct * 16 + l16;
                if (kj > qi) sv = -1e9f;                  // matches ref NEG
                s[ct][r] = sv;
                mx = fmaxf(mx, sv);
            }
#pragma unroll
            for (int d = 1; d < 16; d <<= 1) mx = fmaxf(mx, __shfl_xor(mx, d));
            const float mnew  = fmaxf(m_i[r], mx);
            const float alpha = __expf(m_i[r] - mnew);
            float rs = 0.0f;
#pragma unroll
            for (int ct = 0; ct < 4; ++ct) {
                float p = __expf(s[ct][r] - mnew);
                s[ct][r] = p;
                rs += p;
            }
#pragma unroll
            for (int d = 1; d < 16; d <<= 1) rs += __shfl_xor(rs, d);
            l_i[r] = l_i[r] * alpha + rs;
            m_i[r] = mnew;
#pragma unroll
            for (int ct = 0; ct < 4; ++ct) o[ct][r] *= alpha;
        }

        // P (C-layout regs) -> LDS bf16 (A-layout source)
        const int prow = wave * 16 + quad * 4;
#pragma unroll
        for (int ct = 0; ct < 4; ++ct)
#pragma unroll
            for (int r = 0; r < 4; ++r)
                Ps[(prow + r) * LD + ct * 16 + l16] = (bf16)s[ct][r];
        __syncthreads();

        // O += P @ V
#pragma unroll
        for (int ks = 0; ks < 2; ++ks) {
            bf16x8 a = *(const bf16x8*)&Ps[(wave * 16 + l16) * LD + ks * 32 + quad * 8];
#pragma unroll
            for (int ct = 0; ct < 4; ++ct) {
                bf16x8 b = *(const bf16x8*)&Vt[(ct * 16 + l16) * LD + ks * 32 + quad * 8];
                o[ct] = MFMA(a, b, o[ct]);
            }
        }
        __syncthreads();  // protect Ks/Vt/Ps before next stage
    }

    // epilogue: X[q, cbase + dk] = O / l
    const int row = qb * 64 + wave * 16 + quad * 4;
#pragma unroll
    for (int ct = 0; ct < 4; ++ct) {
#pragma unroll
        for (int r = 0; r < 4; ++r) {
            float val = o[ct][r] / l_i[r];
            X[(row + r) * DMODEL + cbase + ct * 16 + l16] = (bf16)val;
        }
    }
}

// ---------------------------------------------------------------------------
extern "C" void kernel_launch(void* const* d_in, const int* in_sizes, int n_in,
                              void* d_out, int out_size, void* d_ws, size_t ws_size,
                              hipStream_t stream)
{
    const float* q  = (const float*)d_in[0];
    const float* k  = (const float*)d_in[1];
    const float* v  = (const float*)d_in[2];
    // d_in[3] = mask (causal tril) — implemented analytically, not read
    const float* Wq = (const float*)d_in[4];
    const float* bq = (const float*)d_in[5];
    const float* Wk = (const float*)d_in[6];
    const float* bk = (const float*)d_in[7];
    const float* Wv = (const float*)d_in[8];
    const float* bv = (const float*)d_in[9];
    const float* Wo = (const float*)d_in[10];
    const float* bo = (const float*)d_in[11];

    bf16* Qb = (bf16*)d_ws;
    bf16* Kb = Qb + S_LEN * DMODEL;
    bf16* Vb = Kb + S_LEN * DMODEL;
    bf16* Xb = Vb + S_LEN * DMODEL;

    dim3 gg(S_LEN / 64, DMODEL / 64);   // 64 x 12
    dim3 gb(256);

    gemm_bias_kernel<true, false><<<gg, gb, 0, stream>>>(q, Wq, bq, Qb, S_LEN, DMODEL, DMODEL);
    gemm_bias_kernel<true, false><<<gg, gb, 0, stream>>>(k, Wk, bk, Kb, S_LEN, DMODEL, DMODEL);
    gemm_bias_kernel<true, false><<<gg, gb, 0, stream>>>(v, Wv, bv, Vb, S_LEN, DMODEL, DMODEL);

    attn_kernel<<<dim3(S_LEN / 64, NHEAD), gb, 0, stream>>>(Qb, Kb, Vb, Xb);

    gemm_bias_kernel<false, true><<<gg, gb, 0, stream>>>(Xb, Wo, bo, d_out, S_LEN, DMODEL, DMODEL);
}

// Round 2
// 396.749 us; speedup vs baseline: 1.2618x; 1.2618x over previous
//
#include <hip/hip_runtime.h>

typedef __bf16 bf16;
typedef __bf16 bf16x4 __attribute__((ext_vector_type(4)));
typedef __bf16 bf16x8 __attribute__((ext_vector_type(8)));
typedef float  floatx4 __attribute__((ext_vector_type(4)));

#define MFMA16(a,b,c) __builtin_amdgcn_mfma_f32_16x16x32_bf16((a),(b),(c),0,0,0)

static constexpr int S_LEN = 4096;
static constexpr int DM = 768;
static constexpr int NH = 12;
static constexpr int W_ELEMS = 768 * 768;

__device__ __forceinline__ void gld16(const bf16* g, bf16* l) {
    __builtin_amdgcn_global_load_lds(
        (const __attribute__((address_space(1))) void*)g,
        (__attribute__((address_space(3))) void*)l, 16, 0, 0);
}

// ---------------------------------------------------------------------------
// cast fp32 -> bf16, 3 tensors of n elems (n % 1024 == 0), z picks tensor
// ---------------------------------------------------------------------------
__global__ __launch_bounds__(256) void cast3_kernel(
    const float* __restrict__ a, const float* __restrict__ b,
    const float* __restrict__ c, bf16* oa, bf16* ob, bf16* oc, int n)
{
    const int z = blockIdx.y;
    const float* src = z == 0 ? a : (z == 1 ? b : c);
    bf16* dst = z == 0 ? oa : (z == 1 ? ob : oc);
    int i = (blockIdx.x * 256 + threadIdx.x) * 4;
    if (i < n) {
        float4 v = *(const float4*)&src[i];
        bf16x4 o; o[0] = (bf16)v.x; o[1] = (bf16)v.y; o[2] = (bf16)v.z; o[3] = (bf16)v.w;
        *(bf16x4*)&dst[i] = o;
    }
}

// ---------------------------------------------------------------------------
// cast + transpose 768x768 weights: T[n][k] = (bf16)W[k][n], z picks matrix
// ---------------------------------------------------------------------------
__global__ __launch_bounds__(256) void cast_transpose_kernel(
    const float* W0, const float* W1, const float* W2, const float* W3,
    bf16* T0, bf16* T1, bf16* T2, bf16* T3)
{
    const int z = blockIdx.z;
    const float* W = z == 0 ? W0 : (z == 1 ? W1 : (z == 2 ? W2 : W3));
    bf16* T = z == 0 ? T0 : (z == 1 ? T1 : (z == 2 ? T2 : T3));
    __shared__ float Tl[64][65];
    const int tid = threadIdx.x;
    const int k0 = blockIdx.x * 64, n0 = blockIdx.y * 64;
#pragma unroll
    for (int i = 0; i < 4; ++i) {
        int idx = i * 256 + tid;          // 1024 float4-chunks
        int r = idx >> 4, c4 = idx & 15;
        float4 v = *(const float4*)&W[(k0 + r) * 768 + n0 + c4 * 4];
        Tl[c4 * 4 + 0][r] = v.x; Tl[c4 * 4 + 1][r] = v.y;
        Tl[c4 * 4 + 2][r] = v.z; Tl[c4 * 4 + 3][r] = v.w;
    }
    __syncthreads();
#pragma unroll
    for (int i = 0; i < 4; ++i) {
        int idx = i * 256 + tid;
        int c = idx >> 4, r4 = idx & 15;
        bf16x4 o;
        o[0] = (bf16)Tl[c][r4 * 4 + 0]; o[1] = (bf16)Tl[c][r4 * 4 + 1];
        o[2] = (bf16)Tl[c][r4 * 4 + 2]; o[3] = (bf16)Tl[c][r4 * 4 + 3];
        *(bf16x4*)&T[(n0 + c) * 768 + k0 + r4 * 4] = o;
    }
}

// ---------------------------------------------------------------------------
// GEMM (m97 structure): C[M,N] = A[M,K] @ Bt[N,K]^T + bias
// bf16 A/Bt, 128x128 tile, BK=64, global_load_lds 16B staging, 4 waves 2x2.
// ---------------------------------------------------------------------------
template <bool OUT_F32>
__global__ __launch_bounds__(256) void gemm128_kernel(
    const bf16* A0, const bf16* A1, const bf16* A2,
    const bf16* B0, const bf16* B1, const bf16* B2,
    const float* c0, const float* c1, const float* c2,
    void* O0, void* O1, void* O2, int M, int N, int K)
{
    const int z = blockIdx.z;
    const bf16* A = z == 0 ? A0 : (z == 1 ? A1 : A2);
    const bf16* B = z == 0 ? B0 : (z == 1 ? B1 : B2);
    const float* bias = z == 0 ? c0 : (z == 1 ? c1 : c2);
    void* C = z == 0 ? O0 : (z == 1 ? O1 : O2);

    __shared__ bf16 As[128 * 64];   // [m][k] lane-order (unpadded, required by gld_lds)
    __shared__ bf16 Bs[128 * 64];   // [n][k]
    const int tid = threadIdx.x, lane = tid & 63, wave = tid >> 6;
    const int quad = lane >> 4, l16 = lane & 15;
    const int rw = wave >> 1, cw = wave & 1;
    const int m0 = blockIdx.x * 128, n0 = blockIdx.y * 128;

    floatx4 acc[4][4] = {};

    for (int k0 = 0; k0 < K; k0 += 64) {
#pragma unroll
        for (int i = 0; i < 4; ++i) {
            int ch = i * 256 + tid;                 // 1024 chunks of 16 B
            int m = ch >> 3, kg = ch & 7;
            gld16(A + (size_t)(m0 + m) * K + k0 + kg * 8, &As[ch * 8]);
        }
#pragma unroll
        for (int i = 0; i < 4; ++i) {
            int ch = i * 256 + tid;
            int n = ch >> 3, kg = ch & 7;
            gld16(B + (size_t)(n0 + n) * K + k0 + kg * 8, &Bs[ch * 8]);
        }
        __syncthreads();
#pragma unroll
        for (int ks = 0; ks < 2; ++ks) {
            bf16x8 a[4], b[4];
#pragma unroll
            for (int mt = 0; mt < 4; ++mt)
                a[mt] = *(const bf16x8*)&As[(rw * 64 + mt * 16 + l16) * 64 + ks * 32 + quad * 8];
#pragma unroll
            for (int nt = 0; nt < 4; ++nt)
                b[nt] = *(const bf16x8*)&Bs[(cw * 64 + nt * 16 + l16) * 64 + ks * 32 + quad * 8];
#pragma unroll
            for (int mt = 0; mt < 4; ++mt)
#pragma unroll
                for (int nt = 0; nt < 4; ++nt)
                    acc[mt][nt] = MFMA16(a[mt], b[nt], acc[mt][nt]);
        }
        __syncthreads();
    }
#pragma unroll
    for (int mt = 0; mt < 4; ++mt) {
        int row = m0 + rw * 64 + mt * 16 + quad * 4;
#pragma unroll
        for (int nt = 0; nt < 4; ++nt) {
            int col = n0 + cw * 64 + nt * 16 + l16;
            float bv = bias[col];
#pragma unroll
            for (int r = 0; r < 4; ++r) {
                float v = acc[mt][nt][r] + bv;
                if (OUT_F32) ((float*)C)[(size_t)(row + r) * N + col] = v;
                else         ((bf16*)C)[(size_t)(row + r) * N + col] = (bf16)v;
            }
        }
    }
}

// ---------------------------------------------------------------------------
// Causal flash attention, no-running-max softmax (scores bounded: |s/8| < ~6).
// Block = 128 q-rows x 1 head; 4 waves, wave w owns rows w*32..w*32+32.
// All LDS: unpadded 64-elem rows + XOR chunk swizzle -> conflict-free b128.
//   elem(row, col) at row*64 + (((col>>3) ^ (row&7))<<3) + (col&7)
// ---------------------------------------------------------------------------
__global__ __launch_bounds__(256) void attn_kernel(
    const bf16* __restrict__ Q, const bf16* __restrict__ K,
    const bf16* __restrict__ V, bf16* __restrict__ X)
{
    __shared__ bf16 Qs[128 * 64];  // [q][d]
    __shared__ bf16 Ks[64 * 64];   // [key][d]
    __shared__ bf16 Vt[64 * 64];   // [d][key]
    __shared__ bf16 Ps[128 * 64];  // [q][key] (wave-private rows)

    const int h = blockIdx.y;
    const int qb = (int)gridDim.x - 1 - (int)blockIdx.x;   // heavy first
    const int tid = threadIdx.x, lane = tid & 63, wave = tid >> 6;
    const int quad = lane >> 4, l16 = lane & 15, l8 = l16 & 7;
    const int qrow0 = qb * 128;
    const int cb = h * 64;

    // stage Q (coalesced b128 global, swizzled b128 LDS write)
#pragma unroll
    for (int i = 0; i < 4; ++i) {
        int idx = i * 256 + tid;
        int row = idx >> 3, cg = idx & 7;
        bf16x8 d = *(const bf16x8*)&Q[(size_t)(qrow0 + row) * DM + cb + cg * 8];
        *(bf16x8*)&Qs[row * 64 + ((cg ^ (row & 7)) << 3)] = d;
    }

    floatx4 o[2][4] = {};
    float lsum[2][4] = {};
    constexpr float CE = 0.18033688011112042f;  // log2(e) / sqrt(64)

    const int jmax = 2 * qb + 1;
    for (int j = 0; j <= jmax; ++j) {
        // stage K tile [key][d]
#pragma unroll
        for (int i = 0; i < 2; ++i) {
            int idx = i * 256 + tid;
            int row = idx >> 3, cg = idx & 7;
            bf16x8 d = *(const bf16x8*)&K[(size_t)(j * 64 + row) * DM + cb + cg * 8];
            *(bf16x8*)&Ks[row * 64 + ((cg ^ (row & 7)) << 3)] = d;
        }
        // stage V transposed [d][key]: lane gathers an 8-key column strip
        // (coalesced across lanes: d is the fast global axis), one b128 write
#pragma unroll
        for (int i = 0; i < 2; ++i) {
            int idx = i * 256 + tid;
            int dcol = idx & 63, kg = idx >> 6;   // kg 0..7 across i
            bf16x8 t;
#pragma unroll
            for (int u = 0; u < 8; ++u)
                t[u] = V[(size_t)(j * 64 + kg * 8 + u) * DM + cb + dcol];
            *(bf16x8*)&Vt[dcol * 64 + ((kg ^ (dcol & 7)) << 3)] = t;
        }
        __syncthreads();

        // S = Q @ K^T
        floatx4 s[2][4] = {};
#pragma unroll
        for (int ks = 0; ks < 2; ++ks) {
            bf16x8 bfr[4], afr[2];
#pragma unroll
            for (int ct = 0; ct < 4; ++ct)
                bfr[ct] = *(const bf16x8*)&Ks[(ct * 16 + l16) * 64 + (((ks * 4 + quad) ^ l8) << 3)];
#pragma unroll
            for (int mt = 0; mt < 2; ++mt)
                afr[mt] = *(const bf16x8*)&Qs[(wave * 32 + mt * 16 + l16) * 64 + (((ks * 4 + quad) ^ l8) << 3)];
#pragma unroll
            for (int mt = 0; mt < 2; ++mt)
#pragma unroll
                for (int ct = 0; ct < 4; ++ct)
                    s[mt][ct] = MFMA16(afr[mt], bfr[ct], s[mt][ct]);
        }

        // exp2 (no max), mask only where the tile crosses the diagonal,
        // accumulate per-lane row partial sums, scatter P into Ps (swizzled)
#pragma unroll
        for (int mt = 0; mt < 2; ++mt) {
            const int rbase = qrow0 + wave * 32 + mt * 16;
            const bool nomask = (j * 64 + 63) <= rbase;
            const int prow0 = wave * 32 + mt * 16 + quad * 4;
#pragma unroll
            for (int ct = 0; ct < 4; ++ct) {
                const int kj = j * 64 + ct * 16 + l16;
#pragma unroll
                for (int r = 0; r < 4; ++r) {
                    float p = __builtin_amdgcn_exp2f(s[mt][ct][r] * CE);
                    if (!nomask && kj > rbase + quad * 4 + r) p = 0.0f;
                    lsum[mt][r] += p;
                    Ps[(prow0 + r) * 64 +
                       (((ct * 2 + (l16 >> 3)) ^ ((quad * 4 + r) & 7)) << 3) + l8] = (bf16)p;
                }
            }
        }
        // Ps rows are wave-private: no barrier needed (compiler orders LDS deps)

        // O += P @ V
#pragma unroll
        for (int ks = 0; ks < 2; ++ks) {
            bf16x8 bfr[4], afr[2];
#pragma unroll
            for (int ct = 0; ct < 4; ++ct)
                bfr[ct] = *(const bf16x8*)&Vt[(ct * 16 + l16) * 64 + (((ks * 4 + quad) ^ l8) << 3)];
#pragma unroll
            for (int mt = 0; mt < 2; ++mt)
                afr[mt] = *(const bf16x8*)&Ps[(wave * 32 + mt * 16 + l16) * 64 + (((ks * 4 + quad) ^ l8) << 3)];
#pragma unroll
            for (int mt = 0; mt < 2; ++mt)
#pragma unroll
                for (int ct = 0; ct < 4; ++ct)
                    o[mt][ct] = MFMA16(afr[mt], bfr[ct], o[mt][ct]);
        }
        __syncthreads();  // protect Ks/Vt before next stage
    }

    // epilogue: reduce l over the 16 column-lanes, scale, store
#pragma unroll
    for (int mt = 0; mt < 2; ++mt) {
#pragma unroll
        for (int r = 0; r < 4; ++r) {
            float l = lsum[mt][r];
#pragma unroll
            for (int d = 1; d < 16; d <<= 1) l += __shfl_xor(l, d);
            float rl = 1.0f / l;
            const int row = qrow0 + wave * 32 + mt * 16 + quad * 4 + r;
#pragma unroll
            for (int ct = 0; ct < 4; ++ct)
                X[(size_t)row * DM + cb + ct * 16 + l16] = (bf16)(o[mt][ct][r] * rl);
        }
    }
}

// ---------------------------------------------------------------------------
extern "C" void kernel_launch(void* const* d_in, const int* in_sizes, int n_in,
                              void* d_out, int out_size, void* d_ws, size_t ws_size,
                              hipStream_t stream)
{
    const float* q  = (const float*)d_in[0];
    const float* k  = (const float*)d_in[1];
    const float* v  = (const float*)d_in[2];
    // d_in[3] = causal mask, handled analytically
    const float* Wq = (const float*)d_in[4];
    const float* bq = (const float*)d_in[5];
    const float* Wk = (const float*)d_in[6];
    const float* bk = (const float*)d_in[7];
    const float* Wv = (const float*)d_in[8];
    const float* bv = (const float*)d_in[9];
    const float* Wo = (const float*)d_in[10];
    const float* bo = (const float*)d_in[11];

    const size_t NE = (size_t)S_LEN * DM;  // 3,145,728
    bf16* base = (bf16*)d_ws;
    bf16* Qc = base;            // bf16 casts of q,k,v
    bf16* Kc = base + NE;
    bf16* Vc = base + 2 * NE;
    bf16* Qp = base + 3 * NE;   // projections
    bf16* Kp = base + 4 * NE;
    bf16* Vp = base + 5 * NE;
    bf16* Wt = base + 6 * NE;   // 4 transposed bf16 weights
    bf16* Wqt = Wt, *Wkt = Wt + W_ELEMS, *Wvt = Wt + 2 * W_ELEMS, *Wot = Wt + 3 * W_ELEMS;
    bf16* Xb = Qc;              // alias: Qc dead after projections

    cast3_kernel<<<dim3(3072, 3), 256, 0, stream>>>(q, k, v, Qc, Kc, Vc, (int)NE);
    cast_transpose_kernel<<<dim3(12, 12, 4), 256, 0, stream>>>(Wq, Wk, Wv, Wo, Wqt, Wkt, Wvt, Wot);
    gemm128_kernel<false><<<dim3(32, 6, 3), 256, 0, stream>>>(
        Qc, Kc, Vc, Wqt, Wkt, Wvt, bq, bk, bv, Qp, Kp, Vp, S_LEN, DM, DM);
    attn_kernel<<<dim3(32, NH), 256, 0, stream>>>(Qp, Kp, Vp, Xb);
    gemm128_kernel<true><<<dim3(32, 6, 1), 256, 0, stream>>>(
        Xb, Xb, Xb, Wot, Wot, Wot, bo, bo, bo, d_out, d_out, d_out, S_LEN, DM, DM);
}

// Round 3
// 336.159 us; speedup vs baseline: 1.4892x; 1.1802x over previous
//
#include <hip/hip_runtime.h>

typedef __bf16 bf16;
typedef __bf16 bf16x4 __attribute__((ext_vector_type(4)));
typedef __bf16 bf16x8 __attribute__((ext_vector_type(8)));
typedef float  floatx4 __attribute__((ext_vector_type(4)));

#define MFMA16(a,b,c) __builtin_amdgcn_mfma_f32_16x16x32_bf16((a),(b),(c),0,0,0)

static constexpr int S_LEN = 4096;
static constexpr int DM = 768;
static constexpr int NH = 12;
static constexpr int W_ELEMS = 768 * 768;

__device__ __forceinline__ void gld16(const bf16* g, bf16* l) {
    __builtin_amdgcn_global_load_lds(
        (const __attribute__((address_space(1))) void*)g,
        (__attribute__((address_space(3))) void*)l, 16, 0, 0);
}

// ---------------------------------------------------------------------------
// cast fp32 -> bf16, 3 tensors of n elems, z picks tensor
// ---------------------------------------------------------------------------
__global__ __launch_bounds__(256) void cast3_kernel(
    const float* __restrict__ a, const float* __restrict__ b,
    const float* __restrict__ c, bf16* oa, bf16* ob, bf16* oc, int n)
{
    const int z = blockIdx.y;
    const float* src = z == 0 ? a : (z == 1 ? b : c);
    bf16* dst = z == 0 ? oa : (z == 1 ? ob : oc);
    int i = (blockIdx.x * 256 + threadIdx.x) * 4;
    if (i < n) {
        float4 v = *(const float4*)&src[i];
        bf16x4 o; o[0] = (bf16)v.x; o[1] = (bf16)v.y; o[2] = (bf16)v.z; o[3] = (bf16)v.w;
        *(bf16x4*)&dst[i] = o;
    }
}

// ---------------------------------------------------------------------------
// cast + transpose 768x768 weights: T[n][k] = (bf16)W[k][n], z picks matrix
// ---------------------------------------------------------------------------
__global__ __launch_bounds__(256) void cast_transpose_kernel(
    const float* W0, const float* W1, const float* W2, const float* W3,
    bf16* T0, bf16* T1, bf16* T2, bf16* T3)
{
    const int z = blockIdx.z;
    const float* W = z == 0 ? W0 : (z == 1 ? W1 : (z == 2 ? W2 : W3));
    bf16* T = z == 0 ? T0 : (z == 1 ? T1 : (z == 2 ? T2 : T3));
    __shared__ float Tl[64][65];
    const int tid = threadIdx.x;
    const int k0 = blockIdx.x * 64, n0 = blockIdx.y * 64;
#pragma unroll
    for (int i = 0; i < 4; ++i) {
        int idx = i * 256 + tid;
        int r = idx >> 4, c4 = idx & 15;
        float4 v = *(const float4*)&W[(k0 + r) * 768 + n0 + c4 * 4];
        Tl[c4 * 4 + 0][r] = v.x; Tl[c4 * 4 + 1][r] = v.y;
        Tl[c4 * 4 + 2][r] = v.z; Tl[c4 * 4 + 3][r] = v.w;
    }
    __syncthreads();
#pragma unroll
    for (int i = 0; i < 4; ++i) {
        int idx = i * 256 + tid;
        int c = idx >> 4, r4 = idx & 15;
        bf16x4 o;
        o[0] = (bf16)Tl[c][r4 * 4 + 0]; o[1] = (bf16)Tl[c][r4 * 4 + 1];
        o[2] = (bf16)Tl[c][r4 * 4 + 2]; o[3] = (bf16)Tl[c][r4 * 4 + 3];
        *(bf16x4*)&T[(n0 + c) * 768 + k0 + r4 * 4] = o;
    }
}

// ---------------------------------------------------------------------------
// GEMM: C[M,N] = A[M,K] @ Bt[N,K]^T + bias. bf16 A/Bt, 128x128 tile, BK=64.
// Pipelined: double-buffered LDS, prefetch issued BEFORE compute, 1 barrier.
// LDS k-groups XOR-swizzled via the global address (gld_lds slot is fixed,
// fetched data is permuted) -> conflict-free b128 fragment reads.
// ---------------------------------------------------------------------------
template <bool OUT_F32>
__global__ __launch_bounds__(256) void gemm128_kernel(
    const bf16* __restrict__ A0, const bf16* __restrict__ A1, const bf16* __restrict__ A2,
    const bf16* __restrict__ B0, const bf16* __restrict__ B1, const bf16* __restrict__ B2,
    const float* __restrict__ c0, const float* __restrict__ c1, const float* __restrict__ c2,
    void* O0, void* O1, void* O2, int M, int N, int K)
{
    const int z = blockIdx.z;
    const bf16* A = z == 0 ? A0 : (z == 1 ? A1 : A2);
    const bf16* B = z == 0 ? B0 : (z == 1 ? B1 : B2);
    const float* bias = z == 0 ? c0 : (z == 1 ? c1 : c2);
    void* C = z == 0 ? O0 : (z == 1 ? O1 : O2);

    __shared__ bf16 As[2][128 * 64];
    __shared__ bf16 Bs[2][128 * 64];
    const int tid = threadIdx.x, lane = tid & 63, wave = tid >> 6;
    const int quad = lane >> 4, l16 = lane & 15, l8 = l16 & 7;
    const int rw = wave >> 1, cw = wave & 1;
    const int m0 = blockIdx.x * 128, n0 = blockIdx.y * 128;

    floatx4 acc[4][4] = {};

    auto stage = [&](int kt, int buf) {
#pragma unroll
        for (int i = 0; i < 4; ++i) {
            int ch = i * 256 + tid;                 // 1024 chunks of 16 B
            int m = ch >> 3, kg = ch & 7;
            int kgd = kg ^ (m & 7);                 // swizzle via global addr
            gld16(A + (size_t)(m0 + m) * K + kt * 64 + kgd * 8, &As[buf][ch * 8]);
        }
#pragma unroll
        for (int i = 0; i < 4; ++i) {
            int ch = i * 256 + tid;
            int n = ch >> 3, kg = ch & 7;
            int kgd = kg ^ (n & 7);
            gld16(B + (size_t)(n0 + n) * K + kt * 64 + kgd * 8, &Bs[buf][ch * 8]);
        }
    };

    const int NT = K >> 6;
    stage(0, 0);
    __syncthreads();

    for (int kt = 0; kt < NT; ++kt) {
        const int cur = kt & 1;
        if (kt + 1 < NT) stage(kt + 1, cur ^ 1);    // async prefetch, overlaps compute
#pragma unroll
        for (int ks = 0; ks < 2; ++ks) {
            bf16x8 a[4], b[4];
#pragma unroll
            for (int mt = 0; mt < 4; ++mt)
                a[mt] = *(const bf16x8*)&As[cur][(rw * 64 + mt * 16 + l16) * 64 + (((ks * 4 + quad) ^ l8) << 3)];
#pragma unroll
            for (int nt = 0; nt < 4; ++nt)
                b[nt] = *(const bf16x8*)&Bs[cur][(cw * 64 + nt * 16 + l16) * 64 + (((ks * 4 + quad) ^ l8) << 3)];
#pragma unroll
            for (int mt = 0; mt < 4; ++mt)
#pragma unroll
                for (int nt = 0; nt < 4; ++nt)
                    acc[mt][nt] = MFMA16(a[mt], b[nt], acc[mt][nt]);
        }
        __syncthreads();   // drains prefetch (issued one compute-phase ago)
    }
#pragma unroll
    for (int mt = 0; mt < 4; ++mt) {
        int row = m0 + rw * 64 + mt * 16 + quad * 4;
#pragma unroll
        for (int nt = 0; nt < 4; ++nt) {
            int col = n0 + cw * 64 + nt * 16 + l16;
            float bv = bias[col];
#pragma unroll
            for (int r = 0; r < 4; ++r) {
                float v = acc[mt][nt][r] + bv;
                if (OUT_F32) ((float*)C)[(size_t)(row + r) * N + col] = v;
                else         ((bf16*)C)[(size_t)(row + r) * N + col] = (bf16)v;
            }
        }
    }
}

// ---------------------------------------------------------------------------
// Causal flash attention, no-running-max softmax, pipelined K/V staging.
// Block = 128 q-rows x 1 head, 4 waves x 32 rows. Double-buffered Ks/Vt:
// at iter start issue gld_lds K(j+1) + scalar V(j+1) gathers (regs); compute
// tile j; write V regs -> LDS; ONE barrier. All LDS XOR-chunk swizzled.
// ---------------------------------------------------------------------------
__global__ __launch_bounds__(256) void attn_kernel(
    const bf16* __restrict__ Q, const bf16* __restrict__ K,
    const bf16* __restrict__ V, bf16* __restrict__ X)
{
    __shared__ bf16 Qs[128 * 64];    // [q][d]
    __shared__ bf16 Ps[128 * 64];    // [q][key] wave-private rows
    __shared__ bf16 Ks[2][64 * 64];  // [key][d] (gld_lds, addr-swizzled)
    __shared__ bf16 Vt[2][64 * 64];  // [d][key] (reg-gather transpose)

    const int h = blockIdx.y;
    const int qb = (int)gridDim.x - 1 - (int)blockIdx.x;
    const int tid = threadIdx.x, lane = tid & 63, wave = tid >> 6;
    const int quad = lane >> 4, l16 = lane & 15, l8 = l16 & 7;
    const int qrow0 = qb * 128;
    const int cb = h * 64;
    const int jmax = 2 * qb + 1;

    // --- staging helpers -------------------------------------------------
    auto stageK = [&](int j, int buf) {     // 2 gld16/thread, swizzled via addr
#pragma unroll
        for (int i = 0; i < 2; ++i) {
            int ch = i * 256 + tid;                    // 512 chunks
            int row = ch >> 3, kg = ch & 7;
            int kgd = kg ^ (row & 7);
            gld16(K + (size_t)(j * 64 + row) * DM + cb + kgd * 8, &Ks[buf][ch * 8]);
        }
    };
    // V gather: thread loads strips (d=lane, kg=wave) and (d=lane, kg=wave+4)
    auto loadV = [&](int j, bf16 vr[2][8]) {
#pragma unroll
        for (int i = 0; i < 2; ++i) {
            int kg = wave + i * 4;
#pragma unroll
            for (int u = 0; u < 8; ++u)
                vr[i][u] = V[(size_t)(j * 64 + kg * 8 + u) * DM + cb + lane];
        }
    };
    auto writeV = [&](int buf, bf16 vr[2][8]) {
#pragma unroll
        for (int i = 0; i < 2; ++i) {
            int kg = wave + i * 4;
            bf16x8 t;
#pragma unroll
            for (int u = 0; u < 8; ++u) t[u] = vr[i][u];
            *(bf16x8*)&Vt[buf][lane * 64 + ((kg ^ (lane & 7)) << 3)] = t;
        }
    };

    // --- prologue: Q tile + tile 0 ---------------------------------------
    stageK(0, 0);
    bf16 v0[2][8];
    loadV(0, v0);
#pragma unroll
    for (int i = 0; i < 4; ++i) {
        int idx = i * 256 + tid;
        int row = idx >> 3, cg = idx & 7;
        bf16x8 d = *(const bf16x8*)&Q[(size_t)(qrow0 + row) * DM + cb + cg * 8];
        *(bf16x8*)&Qs[row * 64 + ((cg ^ (row & 7)) << 3)] = d;
    }
    writeV(0, v0);
    __syncthreads();

    floatx4 o[2][4] = {};
    float lsum[2][4] = {};
    constexpr float CE = 0.18033688011112042f;  // log2(e) / sqrt(64)

    for (int j = 0; j <= jmax; ++j) {
        const int cur = j & 1;
        bf16 vr[2][8];
        if (j < jmax) {                 // async prefetch of tile j+1
            stageK(j + 1, cur ^ 1);
            loadV(j + 1, vr);
        }

        // S = Q @ K^T
        floatx4 s[2][4] = {};
#pragma unroll
        for (int ks = 0; ks < 2; ++ks) {
            bf16x8 bfr[4], afr[2];
#pragma unroll
            for (int ct = 0; ct < 4; ++ct)
                bfr[ct] = *(const bf16x8*)&Ks[cur][(ct * 16 + l16) * 64 + (((ks * 4 + quad) ^ l8) << 3)];
#pragma unroll
            for (int mt = 0; mt < 2; ++mt)
                afr[mt] = *(const bf16x8*)&Qs[(wave * 32 + mt * 16 + l16) * 64 + (((ks * 4 + quad) ^ l8) << 3)];
#pragma unroll
            for (int mt = 0; mt < 2; ++mt)
#pragma unroll
                for (int ct = 0; ct < 4; ++ct)
                    s[mt][ct] = MFMA16(afr[mt], bfr[ct], s[mt][ct]);
        }

        // exp2 (no running max; |s*scale| bounded), mask at diagonal tiles
#pragma unroll
        for (int mt = 0; mt < 2; ++mt) {
            const int rbase = qrow0 + wave * 32 + mt * 16;
            const bool nomask = (j * 64 + 63) <= rbase;
            const int prow0 = wave * 32 + mt * 16 + quad * 4;
#pragma unroll
            for (int ct = 0; ct < 4; ++ct) {
                const int kj = j * 64 + ct * 16 + l16;
#pragma unroll
                for (int r = 0; r < 4; ++r) {
                    float p = __builtin_amdgcn_exp2f(s[mt][ct][r] * CE);
                    if (!nomask && kj > rbase + quad * 4 + r) p = 0.0f;
                    lsum[mt][r] += p;
                    Ps[(prow0 + r) * 64 +
                       (((ct * 2 + (l16 >> 3)) ^ ((quad * 4 + r) & 7)) << 3) + l8] = (bf16)p;
                }
            }
        }
        // Ps rows wave-private: no barrier

        // O += P @ V
#pragma unroll
        for (int ks = 0; ks < 2; ++ks) {
            bf16x8 bfr[4], afr[2];
#pragma unroll
            for (int ct = 0; ct < 4; ++ct)
                bfr[ct] = *(const bf16x8*)&Vt[cur][(ct * 16 + l16) * 64 + (((ks * 4 + quad) ^ l8) << 3)];
#pragma unroll
            for (int mt = 0; mt < 2; ++mt)
                afr[mt] = *(const bf16x8*)&Ps[(wave * 32 + mt * 16 + l16) * 64 + (((ks * 4 + quad) ^ l8) << 3)];
#pragma unroll
            for (int mt = 0; mt < 2; ++mt)
#pragma unroll
                for (int ct = 0; ct < 4; ++ct)
                    o[mt][ct] = MFMA16(afr[mt], bfr[ct], o[mt][ct]);
        }

        if (j < jmax) writeV(cur ^ 1, vr);  // loads landed during compute
        __syncthreads();                    // drains K prefetch + V writes
    }

    // epilogue
#pragma unroll
    for (int mt = 0; mt < 2; ++mt) {
#pragma unroll
        for (int r = 0; r < 4; ++r) {
            float l = lsum[mt][r];
#pragma unroll
            for (int d = 1; d < 16; d <<= 1) l += __shfl_xor(l, d);
            float rl = 1.0f / l;
            const int row = qrow0 + wave * 32 + mt * 16 + quad * 4 + r;
#pragma unroll
            for (int ct = 0; ct < 4; ++ct)
                X[(size_t)row * DM + cb + ct * 16 + l16] = (bf16)(o[mt][ct][r] * rl);
        }
    }
}

// ---------------------------------------------------------------------------
extern "C" void kernel_launch(void* const* d_in, const int* in_sizes, int n_in,
                              void* d_out, int out_size, void* d_ws, size_t ws_size,
                              hipStream_t stream)
{
    const float* q  = (const float*)d_in[0];
    const float* k  = (const float*)d_in[1];
    const float* v  = (const float*)d_in[2];
    // d_in[3] = causal mask, handled analytically
    const float* Wq = (const float*)d_in[4];
    const float* bq = (const float*)d_in[5];
    const float* Wk = (const float*)d_in[6];
    const float* bk = (const float*)d_in[7];
    const float* Wv = (const float*)d_in[8];
    const float* bv = (const float*)d_in[9];
    const float* Wo = (const float*)d_in[10];
    const float* bo = (const float*)d_in[11];

    const size_t NE = (size_t)S_LEN * DM;
    bf16* base = (bf16*)d_ws;
    bf16* Qc = base;
    bf16* Kc = base + NE;
    bf16* Vc = base + 2 * NE;
    bf16* Qp = base + 3 * NE;
    bf16* Kp = base + 4 * NE;
    bf16* Vp = base + 5 * NE;
    bf16* Wt = base + 6 * NE;
    bf16 *Wqt = Wt, *Wkt = Wt + W_ELEMS, *Wvt = Wt + 2 * W_ELEMS, *Wot = Wt + 3 * W_ELEMS;
    bf16* Xb = Qc;   // Qc dead after projections

    cast3_kernel<<<dim3(3072, 3), 256, 0, stream>>>(q, k, v, Qc, Kc, Vc, (int)NE);
    cast_transpose_kernel<<<dim3(12, 12, 4), 256, 0, stream>>>(Wq, Wk, Wv, Wo, Wqt, Wkt, Wvt, Wot);
    gemm128_kernel<false><<<dim3(32, 6, 3), 256, 0, stream>>>(
        Qc, Kc, Vc, Wqt, Wkt, Wvt, bq, bk, bv, Qp, Kp, Vp, S_LEN, DM, DM);
    attn_kernel<<<dim3(32, NH), 256, 0, stream>>>(Qp, Kp, Vp, Xb);
    gemm128_kernel<true><<<dim3(32, 6, 1), 256, 0, stream>>>(
        Xb, Xb, Xb, Wot, Wot, Wot, bo, bo, bo, d_out, d_out, d_out, S_LEN, DM, DM);
}

// Round 4
// 280.734 us; speedup vs baseline: 1.7832x; 1.1974x over previous
//
#include <hip/hip_runtime.h>

typedef __bf16 bf16;
typedef __bf16 bf16x4 __attribute__((ext_vector_type(4)));
typedef __bf16 bf16x8 __attribute__((ext_vector_type(8)));
typedef float  floatx4 __attribute__((ext_vector_type(4)));

#define MFMA16(a,b,c) __builtin_amdgcn_mfma_f32_16x16x32_bf16((a),(b),(c),0,0,0)

static constexpr int S_LEN = 4096;
static constexpr int DM = 768;
static constexpr int NH = 12;
static constexpr int W_ELEMS = 768 * 768;
static constexpr int PARTS_PER_HEAD = 80;   // sum over qb of ceil((qb+1)/8)

__device__ __forceinline__ void gld16(const bf16* g, bf16* l) {
    __builtin_amdgcn_global_load_lds(
        (const __attribute__((address_space(1))) void*)g,
        (__attribute__((address_space(3))) void*)l, 16, 0, 0);
}

// ---------------------------------------------------------------------------
// prep: y<3 -> cast q/k/v fp32->bf16; y==3 -> cast+transpose 4 weight mats
// ---------------------------------------------------------------------------
__global__ __launch_bounds__(256) void prep_kernel(
    const float* __restrict__ q, const float* __restrict__ k, const float* __restrict__ v,
    const float* __restrict__ W0, const float* __restrict__ W1,
    const float* __restrict__ W2, const float* __restrict__ W3,
    bf16* Qc, bf16* Kc, bf16* Vc,
    bf16* T0, bf16* T1, bf16* T2, bf16* T3, int n)
{
    const int y = blockIdx.y;
    const int tid = threadIdx.x;
    if (y < 3) {
        const float* src = y == 0 ? q : (y == 1 ? k : v);
        bf16* dst = y == 0 ? Qc : (y == 1 ? Kc : Vc);
        int i = (blockIdx.x * 256 + tid) * 4;
        if (i < n) {
            float4 w = *(const float4*)&src[i];
            bf16x4 o; o[0] = (bf16)w.x; o[1] = (bf16)w.y; o[2] = (bf16)w.z; o[3] = (bf16)w.w;
            *(bf16x4*)&dst[i] = o;
        }
        return;
    }
    // transpose path: 4 matrices x 144 tiles
    int x = blockIdx.x;
    if (x >= 576) return;
    const int mat = x / 144, t = x % 144;
    const float* W = mat == 0 ? W0 : (mat == 1 ? W1 : (mat == 2 ? W2 : W3));
    bf16* T = mat == 0 ? T0 : (mat == 1 ? T1 : (mat == 2 ? T2 : T3));
    const int k0 = (t / 12) * 64, n0 = (t % 12) * 64;
    __shared__ float Tl[64][65];
#pragma unroll
    for (int i = 0; i < 4; ++i) {
        int idx = i * 256 + tid;
        int r = idx >> 4, c4 = idx & 15;
        float4 w = *(const float4*)&W[(k0 + r) * 768 + n0 + c4 * 4];
        Tl[c4 * 4 + 0][r] = w.x; Tl[c4 * 4 + 1][r] = w.y;
        Tl[c4 * 4 + 2][r] = w.z; Tl[c4 * 4 + 3][r] = w.w;
    }
    __syncthreads();
#pragma unroll
    for (int i = 0; i < 4; ++i) {
        int idx = i * 256 + tid;
        int c = idx >> 4, r4 = idx & 15;
        bf16x4 o;
        o[0] = (bf16)Tl[c][r4 * 4 + 0]; o[1] = (bf16)Tl[c][r4 * 4 + 1];
        o[2] = (bf16)Tl[c][r4 * 4 + 2]; o[3] = (bf16)Tl[c][r4 * 4 + 3];
        *(bf16x4*)&T[(n0 + c) * 768 + k0 + r4 * 4] = o;
    }
}

// ---------------------------------------------------------------------------
// GEMM: C[M,N] = A[M,K] @ Bt[N,K]^T + bias. 128x128 tile, BK=64, pipelined
// dbuf + gld_lds(16B) prefetch, addr-side XOR swizzle -> conflict-free b128.
// ---------------------------------------------------------------------------
template <bool OUT_F32>
__global__ __launch_bounds__(256) void gemm128_kernel(
    const bf16* __restrict__ A0, const bf16* __restrict__ A1, const bf16* __restrict__ A2,
    const bf16* __restrict__ B0, const bf16* __restrict__ B1, const bf16* __restrict__ B2,
    const float* __restrict__ c0, const float* __restrict__ c1, const float* __restrict__ c2,
    void* O0, void* O1, void* O2, int M, int N, int K)
{
    const int z = blockIdx.z;
    const bf16* A = z == 0 ? A0 : (z == 1 ? A1 : A2);
    const bf16* B = z == 0 ? B0 : (z == 1 ? B1 : B2);
    const float* bias = z == 0 ? c0 : (z == 1 ? c1 : c2);
    void* C = z == 0 ? O0 : (z == 1 ? O1 : O2);

    __shared__ bf16 As[2][128 * 64];
    __shared__ bf16 Bs[2][128 * 64];
    const int tid = threadIdx.x, lane = tid & 63, wave = tid >> 6;
    const int quad = lane >> 4, l16 = lane & 15, l8 = l16 & 7;
    const int rw = wave >> 1, cw = wave & 1;
    const int m0 = blockIdx.x * 128, n0 = blockIdx.y * 128;

    floatx4 acc[4][4] = {};

    auto stage = [&](int kt, int buf) {
#pragma unroll
        for (int i = 0; i < 4; ++i) {
            int ch = i * 256 + tid;
            int m = ch >> 3, kg = ch & 7;
            int kgd = kg ^ (m & 7);
            gld16(A + (size_t)(m0 + m) * K + kt * 64 + kgd * 8, &As[buf][ch * 8]);
        }
#pragma unroll
        for (int i = 0; i < 4; ++i) {
            int ch = i * 256 + tid;
            int n = ch >> 3, kg = ch & 7;
            int kgd = kg ^ (n & 7);
            gld16(B + (size_t)(n0 + n) * K + kt * 64 + kgd * 8, &Bs[buf][ch * 8]);
        }
    };

    const int NT = K >> 6;
    stage(0, 0);
    __syncthreads();

    for (int kt = 0; kt < NT; ++kt) {
        const int cur = kt & 1;
        if (kt + 1 < NT) stage(kt + 1, cur ^ 1);
#pragma unroll
        for (int ks = 0; ks < 2; ++ks) {
            bf16x8 a[4], b[4];
#pragma unroll
            for (int mt = 0; mt < 4; ++mt)
                a[mt] = *(const bf16x8*)&As[cur][(rw * 64 + mt * 16 + l16) * 64 + (((ks * 4 + quad) ^ l8) << 3)];
#pragma unroll
            for (int nt = 0; nt < 4; ++nt)
                b[nt] = *(const bf16x8*)&Bs[cur][(cw * 64 + nt * 16 + l16) * 64 + (((ks * 4 + quad) ^ l8) << 3)];
#pragma unroll
            for (int mt = 0; mt < 4; ++mt)
#pragma unroll
                for (int nt = 0; nt < 4; ++nt)
                    acc[mt][nt] = MFMA16(a[mt], b[nt], acc[mt][nt]);
        }
        __syncthreads();
    }
#pragma unroll
    for (int mt = 0; mt < 4; ++mt) {
        int row = m0 + rw * 64 + mt * 16 + quad * 4;
#pragma unroll
        for (int nt = 0; nt < 4; ++nt) {
            int col = n0 + cw * 64 + nt * 16 + l16;
            float bv = bias[col];
#pragma unroll
            for (int r = 0; r < 4; ++r) {
                float v = acc[mt][nt][r] + bv;
                if (OUT_F32) ((float*)C)[(size_t)(row + r) * N + col] = v;
                else         ((bf16*)C)[(size_t)(row + r) * N + col] = (bf16)v;
            }
        }
    }
}

// ---------------------------------------------------------------------------
// Split-K causal flash attention. Block = (128 q-rows, head, chunk of <=16
// K-tiles). No-max softmax => partials are ADDITIVE: block writes unnormalized
// fp32 O_part (128x64) + l_part (128); combine kernel sums & normalizes.
// Q fragments live in registers (wave-private rows). LDS 48 KB -> 3 blocks/CU.
// part index within head: qb<8: qb | qb<16: 8+(qb-8)*2+c | qb<24: 24+(qb-16)*3+c
//                       | else: 48+(qb-24)*4+c
// ---------------------------------------------------------------------------
__global__ __launch_bounds__(256) void attn_kernel(
    const bf16* __restrict__ Q, const bf16* __restrict__ K,
    const bf16* __restrict__ V, float* __restrict__ Opart,
    float* __restrict__ Lpart)
{
    __shared__ bf16 Ps[128 * 64];    // [q][key] wave-private rows
    __shared__ bf16 Ks[2][64 * 64];  // [key][d] gld_lds, addr-swizzled
    __shared__ bf16 Vt[2][64 * 64];  // [d][key] reg-gather transpose

    const int h = blockIdx.y;
    const int idx = PARTS_PER_HEAD - 1 - (int)blockIdx.x;   // heavy chunks first
    int qb, c;
    if (idx < 8)       { qb = idx;                    c = 0;            }
    else if (idx < 24) { qb = 8  + ((idx - 8) >> 1);  c = (idx - 8) & 1; }
    else if (idx < 48) { qb = 16 + (idx - 24) / 3;    c = (idx - 24) % 3; }
    else               { qb = 24 + ((idx - 48) >> 2); c = (idx - 48) & 3; }
    const int jstart = c * 16;
    const int jend0  = 2 * qb + 2;
    const int jend   = (jstart + 16 < jend0) ? jstart + 16 : jend0;  // exclusive

    const int tid = threadIdx.x, lane = tid & 63, wave = tid >> 6;
    const int quad = lane >> 4, l16 = lane & 15, l8 = l16 & 7;
    const int qrow0 = qb * 128;
    const int cb = h * 64;

    auto stageK = [&](int j, int buf) {
#pragma unroll
        for (int i = 0; i < 2; ++i) {
            int ch = i * 256 + tid;
            int row = ch >> 3, kg = ch & 7;
            int kgd = kg ^ (row & 7);
            gld16(K + (size_t)(j * 64 + row) * DM + cb + kgd * 8, &Ks[buf][ch * 8]);
        }
    };
    auto loadV = [&](int j, bf16 vr[2][8]) {
#pragma unroll
        for (int i = 0; i < 2; ++i) {
            int kg = wave + i * 4;
#pragma unroll
            for (int u = 0; u < 8; ++u)
                vr[i][u] = V[(size_t)(j * 64 + kg * 8 + u) * DM + cb + lane];
        }
    };
    auto writeV = [&](int buf, bf16 vr[2][8]) {
#pragma unroll
        for (int i = 0; i < 2; ++i) {
            int kg = wave + i * 4;
            bf16x8 t;
#pragma unroll
            for (int u = 0; u < 8; ++u) t[u] = vr[i][u];
            *(bf16x8*)&Vt[buf][lane * 64 + ((kg ^ (lane & 7)) << 3)] = t;
        }
    };

    // Q fragments -> registers (wave-private rows), once per block
    bf16x8 qreg[2][2];
#pragma unroll
    for (int mt = 0; mt < 2; ++mt)
#pragma unroll
        for (int ks = 0; ks < 2; ++ks)
            qreg[mt][ks] = *(const bf16x8*)&Q[(size_t)(qrow0 + wave * 32 + mt * 16 + l16) * DM
                                             + cb + ks * 32 + quad * 8];

    // prologue: stage tile jstart
    stageK(jstart, 0);
    bf16 v0[2][8];
    loadV(jstart, v0);
    writeV(0, v0);
    __syncthreads();

    floatx4 o[2][4] = {};
    float lsum[2][4] = {};
    constexpr float CE = 0.18033688011112042f;  // log2(e) / sqrt(64)

    for (int j = jstart; j < jend; ++j) {
        const int cur = (j - jstart) & 1;
        bf16 vr[2][8];
        if (j + 1 < jend) {
            stageK(j + 1, cur ^ 1);
            loadV(j + 1, vr);
        }

        // S = Q @ K^T
        floatx4 s[2][4] = {};
#pragma unroll
        for (int ks = 0; ks < 2; ++ks) {
            bf16x8 bfr[4];
#pragma unroll
            for (int ct = 0; ct < 4; ++ct)
                bfr[ct] = *(const bf16x8*)&Ks[cur][(ct * 16 + l16) * 64 + (((ks * 4 + quad) ^ l8) << 3)];
#pragma unroll
            for (int mt = 0; mt < 2; ++mt)
#pragma unroll
                for (int ct = 0; ct < 4; ++ct)
                    s[mt][ct] = MFMA16(qreg[mt][ks], bfr[ct], s[mt][ct]);
        }

        // exp2 softmax (no max; scores bounded), mask at diagonal tiles
#pragma unroll
        for (int mt = 0; mt < 2; ++mt) {
            const int rbase = qrow0 + wave * 32 + mt * 16;
            const bool nomask = (j * 64 + 63) <= rbase;
            const int prow0 = wave * 32 + mt * 16 + quad * 4;
#pragma unroll
            for (int ct = 0; ct < 4; ++ct) {
                const int kj = j * 64 + ct * 16 + l16;
#pragma unroll
                for (int r = 0; r < 4; ++r) {
                    float p = __builtin_amdgcn_exp2f(s[mt][ct][r] * CE);
                    if (!nomask && kj > rbase + quad * 4 + r) p = 0.0f;
                    lsum[mt][r] += p;
                    Ps[(prow0 + r) * 64 +
                       (((ct * 2 + (l16 >> 3)) ^ ((quad * 4 + r) & 7)) << 3) + l8] = (bf16)p;
                }
            }
        }
        // Ps rows wave-private: no barrier

        // O += P @ V
#pragma unroll
        for (int ks = 0; ks < 2; ++ks) {
            bf16x8 bfr[4], afr[2];
#pragma unroll
            for (int ct = 0; ct < 4; ++ct)
                bfr[ct] = *(const bf16x8*)&Vt[cur][(ct * 16 + l16) * 64 + (((ks * 4 + quad) ^ l8) << 3)];
#pragma unroll
            for (int mt = 0; mt < 2; ++mt)
                afr[mt] = *(const bf16x8*)&Ps[(wave * 32 + mt * 16 + l16) * 64 + (((ks * 4 + quad) ^ l8) << 3)];
#pragma unroll
            for (int mt = 0; mt < 2; ++mt)
#pragma unroll
                for (int ct = 0; ct < 4; ++ct)
                    o[mt][ct] = MFMA16(afr[mt], bfr[ct], o[mt][ct]);
        }

        if (j + 1 < jend) writeV(cur ^ 1, vr);
        __syncthreads();
    }

    // epilogue: write unnormalized fp32 partial + per-row l
    float* Op = Opart + (size_t)(h * PARTS_PER_HEAD + idx) * 128 * 64;
    float* Lp = Lpart + (size_t)(h * PARTS_PER_HEAD + idx) * 128;
#pragma unroll
    for (int mt = 0; mt < 2; ++mt) {
#pragma unroll
        for (int r = 0; r < 4; ++r) {
            float l = lsum[mt][r];
#pragma unroll
            for (int d = 1; d < 16; d <<= 1) l += __shfl_xor(l, d);
            const int rl = wave * 32 + mt * 16 + quad * 4 + r;
#pragma unroll
            for (int ct = 0; ct < 4; ++ct)
                Op[rl * 64 + ct * 16 + l16] = o[mt][ct][r];
            if (l16 == 0) Lp[rl] = l;
        }
    }
}

// ---------------------------------------------------------------------------
// combine: X[qb rows, head] = (sum of partial O) / (sum of partial l), bf16
// ---------------------------------------------------------------------------
__global__ __launch_bounds__(256) void attn_combine_kernel(
    const float* __restrict__ Opart, const float* __restrict__ Lpart,
    bf16* __restrict__ X)
{
    const int qb = blockIdx.x, h = blockIdx.y;
    const int nc = 1 + (qb >> 3);
    const int base = (qb < 8) ? qb
                   : (qb < 16) ? 8 + (qb - 8) * 2
                   : (qb < 24) ? 24 + (qb - 16) * 3
                   : 48 + (qb - 24) * 4;
    const float* Op0 = Opart + (size_t)(h * PARTS_PER_HEAD + base) * 128 * 64;
    const float* Lp0 = Lpart + (size_t)(h * PARTS_PER_HEAD + base) * 128;

    for (int e = threadIdx.x * 4; e < 128 * 64; e += 1024) {
        const int row = e >> 6, col = e & 63;
        float4 acc = {0.f, 0.f, 0.f, 0.f};
        float l = 0.f;
        for (int p = 0; p < nc; ++p) {
            float4 w = *(const float4*)&Op0[p * 128 * 64 + e];
            acc.x += w.x; acc.y += w.y; acc.z += w.z; acc.w += w.w;
            l += Lp0[p * 128 + row];
        }
        const float rl = 1.0f / l;
        bf16x4 ov;
        ov[0] = (bf16)(acc.x * rl); ov[1] = (bf16)(acc.y * rl);
        ov[2] = (bf16)(acc.z * rl); ov[3] = (bf16)(acc.w * rl);
        *(bf16x4*)&X[(size_t)(qb * 128 + row) * DM + h * 64 + col] = ov;
    }
}

// ---------------------------------------------------------------------------
extern "C" void kernel_launch(void* const* d_in, const int* in_sizes, int n_in,
                              void* d_out, int out_size, void* d_ws, size_t ws_size,
                              hipStream_t stream)
{
    const float* q  = (const float*)d_in[0];
    const float* k  = (const float*)d_in[1];
    const float* v  = (const float*)d_in[2];
    // d_in[3] = causal mask, handled analytically
    const float* Wq = (const float*)d_in[4];
    const float* bq = (const float*)d_in[5];
    const float* Wk = (const float*)d_in[6];
    const float* bk = (const float*)d_in[7];
    const float* Wv = (const float*)d_in[8];
    const float* bv = (const float*)d_in[9];
    const float* Wo = (const float*)d_in[10];
    const float* bo = (const float*)d_in[11];

    const size_t NE = (size_t)S_LEN * DM;
    bf16* base = (bf16*)d_ws;
    bf16* Qc = base;
    bf16* Kc = base + NE;
    bf16* Vc = base + 2 * NE;
    bf16* Qp = base + 3 * NE;
    bf16* Kp = base + 4 * NE;
    bf16* Vp = base + 5 * NE;
    bf16* Wt = base + 6 * NE;
    bf16 *Wqt = Wt, *Wkt = Wt + W_ELEMS, *Wvt = Wt + 2 * W_ELEMS, *Wot = Wt + 3 * W_ELEMS;
    float* Opart = (float*)(Wt + 4 * W_ELEMS);                   // 960*128*64 fp32
    float* Lpart = Opart + (size_t)NH * PARTS_PER_HEAD * 128 * 64;
    bf16* Xb = Qc;   // Qc dead after projections

    prep_kernel<<<dim3(3072, 4), 256, 0, stream>>>(
        q, k, v, Wq, Wk, Wv, Wo, Qc, Kc, Vc, Wqt, Wkt, Wvt, Wot, (int)NE);
    gemm128_kernel<false><<<dim3(32, 6, 3), 256, 0, stream>>>(
        Qc, Kc, Vc, Wqt, Wkt, Wvt, bq, bk, bv, Qp, Kp, Vp, S_LEN, DM, DM);
    attn_kernel<<<dim3(PARTS_PER_HEAD, NH), 256, 0, stream>>>(Qp, Kp, Vp, Opart, Lpart);
    attn_combine_kernel<<<dim3(32, NH), 256, 0, stream>>>(Opart, Lpart, Xb);
    gemm128_kernel<true><<<dim3(32, 6, 1), 256, 0, stream>>>(
        Xb, Xb, Xb, Wot, Wot, Wot, bo, bo, bo, d_out, d_out, d_out, S_LEN, DM, DM);
}

// Round 5
// 268.945 us; speedup vs baseline: 1.8613x; 1.0438x over previous
//
#include <hip/hip_runtime.h>

typedef __bf16 bf16;
typedef __bf16 bf16x4 __attribute__((ext_vector_type(4)));
typedef __bf16 bf16x8 __attribute__((ext_vector_type(8)));
typedef float  floatx4 __attribute__((ext_vector_type(4)));

#define MFMA16(a,b,c) __builtin_amdgcn_mfma_f32_16x16x32_bf16((a),(b),(c),0,0,0)

static constexpr int S_LEN = 4096;
static constexpr int DM = 768;
static constexpr int NH = 12;
static constexpr int W_ELEMS = 768 * 768;
static constexpr int PARTS_PER_HEAD = 80;   // sum over qb of ceil((qb+1)/8)
static constexpr float CE = 0.18033688011112042f;  // log2(e)/sqrt(64), folded into Q proj

__device__ __forceinline__ void gld16(const bf16* g, bf16* l) {
    __builtin_amdgcn_global_load_lds(
        (const __attribute__((address_space(1))) void*)g,
        (__attribute__((address_space(3))) void*)l, 16, 0, 0);
}

// ---------------------------------------------------------------------------
// prep: y<3 -> cast q/k/v fp32->bf16; y==3 -> cast+transpose 4 weight mats
// ---------------------------------------------------------------------------
__global__ __launch_bounds__(256) void prep_kernel(
    const float* __restrict__ q, const float* __restrict__ k, const float* __restrict__ v,
    const float* __restrict__ W0, const float* __restrict__ W1,
    const float* __restrict__ W2, const float* __restrict__ W3,
    bf16* Qc, bf16* Kc, bf16* Vc,
    bf16* T0, bf16* T1, bf16* T2, bf16* T3, int n)
{
    const int y = blockIdx.y;
    const int tid = threadIdx.x;
    if (y < 3) {
        const float* src = y == 0 ? q : (y == 1 ? k : v);
        bf16* dst = y == 0 ? Qc : (y == 1 ? Kc : Vc);
        int i = (blockIdx.x * 256 + tid) * 4;
        if (i < n) {
            float4 w = *(const float4*)&src[i];
            bf16x4 o; o[0] = (bf16)w.x; o[1] = (bf16)w.y; o[2] = (bf16)w.z; o[3] = (bf16)w.w;
            *(bf16x4*)&dst[i] = o;
        }
        return;
    }
    int x = blockIdx.x;
    if (x >= 576) return;
    const int mat = x / 144, t = x % 144;
    const float* W = mat == 0 ? W0 : (mat == 1 ? W1 : (mat == 2 ? W2 : W3));
    bf16* T = mat == 0 ? T0 : (mat == 1 ? T1 : (mat == 2 ? T2 : T3));
    const int k0 = (t / 12) * 64, n0 = (t % 12) * 64;
    __shared__ float Tl[64][65];
#pragma unroll
    for (int i = 0; i < 4; ++i) {
        int idx = i * 256 + tid;
        int r = idx >> 4, c4 = idx & 15;
        float4 w = *(const float4*)&W[(k0 + r) * 768 + n0 + c4 * 4];
        Tl[c4 * 4 + 0][r] = w.x; Tl[c4 * 4 + 1][r] = w.y;
        Tl[c4 * 4 + 2][r] = w.z; Tl[c4 * 4 + 3][r] = w.w;
    }
    __syncthreads();
#pragma unroll
    for (int i = 0; i < 4; ++i) {
        int idx = i * 256 + tid;
        int c = idx >> 4, r4 = idx & 15;
        bf16x4 o;
        o[0] = (bf16)Tl[c][r4 * 4 + 0]; o[1] = (bf16)Tl[c][r4 * 4 + 1];
        o[2] = (bf16)Tl[c][r4 * 4 + 2]; o[3] = (bf16)Tl[c][r4 * 4 + 3];
        *(bf16x4*)&T[(n0 + c) * 768 + k0 + r4 * 4] = o;
    }
}

// ---------------------------------------------------------------------------
// GEMM: C[M,N] = (A[M,K] @ Bt[N,K]^T + bias) * scale(z). 128x128, BK=64,
// pipelined dbuf + gld_lds(16B), addr-side XOR swizzle. scale applied only
// for z==0 (folds softmax's log2(e)/8 into the Q projection).
// ---------------------------------------------------------------------------
template <bool OUT_F32>
__global__ __launch_bounds__(256) void gemm128_kernel(
    const bf16* __restrict__ A0, const bf16* __restrict__ A1, const bf16* __restrict__ A2,
    const bf16* __restrict__ B0, const bf16* __restrict__ B1, const bf16* __restrict__ B2,
    const float* __restrict__ c0, const float* __restrict__ c1, const float* __restrict__ c2,
    void* O0, void* O1, void* O2, int M, int N, int K, float qscale)
{
    const int z = blockIdx.z;
    const bf16* A = z == 0 ? A0 : (z == 1 ? A1 : A2);
    const bf16* B = z == 0 ? B0 : (z == 1 ? B1 : B2);
    const float* bias = z == 0 ? c0 : (z == 1 ? c1 : c2);
    void* C = z == 0 ? O0 : (z == 1 ? O1 : O2);
    const float osc = (z == 0) ? qscale : 1.0f;

    __shared__ bf16 As[2][128 * 64];
    __shared__ bf16 Bs[2][128 * 64];
    const int tid = threadIdx.x, lane = tid & 63, wave = tid >> 6;
    const int quad = lane >> 4, l16 = lane & 15, l8 = l16 & 7;
    const int rw = wave >> 1, cw = wave & 1;
    const int m0 = blockIdx.x * 128, n0 = blockIdx.y * 128;

    floatx4 acc[4][4] = {};

    auto stage = [&](int kt, int buf) {
#pragma unroll
        for (int i = 0; i < 4; ++i) {
            int ch = i * 256 + tid;
            int m = ch >> 3, kg = ch & 7;
            int kgd = kg ^ (m & 7);
            gld16(A + (size_t)(m0 + m) * K + kt * 64 + kgd * 8, &As[buf][ch * 8]);
        }
#pragma unroll
        for (int i = 0; i < 4; ++i) {
            int ch = i * 256 + tid;
            int n = ch >> 3, kg = ch & 7;
            int kgd = kg ^ (n & 7);
            gld16(B + (size_t)(n0 + n) * K + kt * 64 + kgd * 8, &Bs[buf][ch * 8]);
        }
    };

    const int NT = K >> 6;
    stage(0, 0);
    __syncthreads();

    for (int kt = 0; kt < NT; ++kt) {
        const int cur = kt & 1;
        if (kt + 1 < NT) stage(kt + 1, cur ^ 1);
#pragma unroll
        for (int ks = 0; ks < 2; ++ks) {
            bf16x8 a[4], b[4];
#pragma unroll
            for (int mt = 0; mt < 4; ++mt)
                a[mt] = *(const bf16x8*)&As[cur][(rw * 64 + mt * 16 + l16) * 64 + (((ks * 4 + quad) ^ l8) << 3)];
#pragma unroll
            for (int nt = 0; nt < 4; ++nt)
                b[nt] = *(const bf16x8*)&Bs[cur][(cw * 64 + nt * 16 + l16) * 64 + (((ks * 4 + quad) ^ l8) << 3)];
#pragma unroll
            for (int mt = 0; mt < 4; ++mt)
#pragma unroll
                for (int nt = 0; nt < 4; ++nt)
                    acc[mt][nt] = MFMA16(a[mt], b[nt], acc[mt][nt]);
        }
        __syncthreads();
    }
#pragma unroll
    for (int mt = 0; mt < 4; ++mt) {
        int row = m0 + rw * 64 + mt * 16 + quad * 4;
#pragma unroll
        for (int nt = 0; nt < 4; ++nt) {
            int col = n0 + cw * 64 + nt * 16 + l16;
            float bv = bias[col];
#pragma unroll
            for (int r = 0; r < 4; ++r) {
                float v = (acc[mt][nt][r] + bv) * osc;
                if (OUT_F32) ((float*)C)[(size_t)(row + r) * N + col] = v;
                else         ((bf16*)C)[(size_t)(row + r) * N + col] = (bf16)v;
            }
        }
    }
}

// ---------------------------------------------------------------------------
// Split-K causal flash attention, S^T formulation.
// S^T = K_tile · Q_tile^T (swapped MFMA operands; qreg serves as B directly).
// Lane then holds 4 CONSECUTIVE k for a fixed q -> P written as 8 b64 packed
// stores into Ps[q][k]; PV reads Ps as A with the proven b128 swizzle.
// Q prescaled by log2(e)/8 in the projection -> softmax = exp2 only.
// Vt single-buffered (regs hold prefetch) -> LDS 40KB -> 4 blocks/CU.
// ---------------------------------------------------------------------------
__global__ __launch_bounds__(256) void attn_kernel(
    const bf16* __restrict__ Q, const bf16* __restrict__ K,
    const bf16* __restrict__ V, float* __restrict__ Opart,
    float* __restrict__ Lpart)
{
    __shared__ bf16 Ps[128 * 64];    // [q][key] wave-private rows, chunk-swizzled
    __shared__ bf16 Ks[2][64 * 64];  // [key][d] gld_lds dbuf, addr-swizzled
    __shared__ bf16 Vt[64 * 64];     // [d][key] single buffer, reg-gather transpose

    const int h = blockIdx.y;
    const int idx = PARTS_PER_HEAD - 1 - (int)blockIdx.x;   // heavy chunks first
    int qb, c;
    if (idx < 8)       { qb = idx;                    c = 0;            }
    else if (idx < 24) { qb = 8  + ((idx - 8) >> 1);  c = (idx - 8) & 1; }
    else if (idx < 48) { qb = 16 + (idx - 24) / 3;    c = (idx - 24) % 3; }
    else               { qb = 24 + ((idx - 48) >> 2); c = (idx - 48) & 3; }
    const int jstart = c * 16;
    const int jend0  = 2 * qb + 2;
    const int jend   = (jstart + 16 < jend0) ? jstart + 16 : jend0;  // exclusive

    const int tid = threadIdx.x, lane = tid & 63, wave = tid >> 6;
    const int quad = lane >> 4, l16 = lane & 15, l8 = l16 & 7;
    const int qrow0 = qb * 128;
    const int cb = h * 64;

    auto stageK = [&](int j, int buf) {
#pragma unroll
        for (int i = 0; i < 2; ++i) {
            int ch = i * 256 + tid;
            int row = ch >> 3, kg = ch & 7;
            int kgd = kg ^ (row & 7);
            gld16(K + (size_t)(j * 64 + row) * DM + cb + kgd * 8, &Ks[buf][ch * 8]);
        }
    };
    auto loadV = [&](int j, bf16 vr[2][8]) {
#pragma unroll
        for (int i = 0; i < 2; ++i) {
            int kg = wave + i * 4;
#pragma unroll
            for (int u = 0; u < 8; ++u)
                vr[i][u] = V[(size_t)(j * 64 + kg * 8 + u) * DM + cb + lane];
        }
    };
    auto writeV = [&](bf16 vr[2][8]) {
#pragma unroll
        for (int i = 0; i < 2; ++i) {
            int kg = wave + i * 4;
            bf16x8 t;
#pragma unroll
            for (int u = 0; u < 8; ++u) t[u] = vr[i][u];
            *(bf16x8*)&Vt[lane * 64 + ((kg ^ (lane & 7)) << 3)] = t;
        }
    };

    // Q fragments (A-layout == B-layout of Q^T element-wise): wave-private rows
    bf16x8 qreg[2][2];
#pragma unroll
    for (int mt = 0; mt < 2; ++mt)
#pragma unroll
        for (int ks = 0; ks < 2; ++ks)
            qreg[mt][ks] = *(const bf16x8*)&Q[(size_t)(qrow0 + wave * 32 + mt * 16 + l16) * DM
                                             + cb + ks * 32 + quad * 8];

    // prologue
    stageK(jstart, 0);
    bf16 v0[2][8];
    loadV(jstart, v0);
    writeV(v0);
    __syncthreads();

    floatx4 o[2][4] = {};
    float lsum[2] = {0.f, 0.f};
    // Ps row base (elems) for this lane's q, and iter-invariant write offsets
    const int prowbase = (wave * 32 + l16) * 64;           // + mt*16*64
    const int psub = (quad & 1) * 4;
    const int c16base = (quad >> 1);

    for (int j = jstart; j < jend; ++j) {
        const int cur = (j - jstart) & 1;
        bf16 vr[2][8];
        if (j + 1 < jend) {
            stageK(j + 1, cur ^ 1);
            loadV(j + 1, vr);
        }

        // S^T = K @ Q^T   (lane: k = ct*16 + quad*4 + r, q = subtile + l16)
        floatx4 st[2][4] = {};
#pragma unroll
        for (int ks = 0; ks < 2; ++ks) {
            bf16x8 kfr[4];
#pragma unroll
            for (int ct = 0; ct < 4; ++ct)
                kfr[ct] = *(const bf16x8*)&Ks[cur][(ct * 16 + l16) * 64 + (((ks * 4 + quad) ^ l8) << 3)];
#pragma unroll
            for (int mt = 0; mt < 2; ++mt)
#pragma unroll
                for (int ct = 0; ct < 4; ++ct)
                    st[mt][ct] = MFMA16(kfr[ct], qreg[mt][ks], st[mt][ct]);
        }

        // softmax: p = exp2(st) (Q prescaled); pack 4 consecutive-k -> b64
#pragma unroll
        for (int mt = 0; mt < 2; ++mt) {
            const int qs0 = qrow0 + wave * 32 + mt * 16;
            const int pb = prowbase + mt * 16 * 64;
            float lp = 0.f;
            if ((j * 64 + 63) <= qs0) {          // interior tile: no mask ops
#pragma unroll
                for (int ct = 0; ct < 4; ++ct) {
                    bf16x4 pk;
#pragma unroll
                    for (int r = 0; r < 4; ++r) {
                        float p = __builtin_amdgcn_exp2f(st[mt][ct][r]);
                        lp += p; pk[r] = (bf16)p;
                    }
                    *(bf16x4*)&Ps[pb + ((((ct * 2 + c16base) ^ l8) << 3) + psub)] = pk;
                }
            } else {                              // diagonal tile: mask k > q
                const int qg = qs0 + l16;
#pragma unroll
                for (int ct = 0; ct < 4; ++ct) {
                    const int kg0 = j * 64 + ct * 16 + quad * 4;
                    bf16x4 pk;
#pragma unroll
                    for (int r = 0; r < 4; ++r) {
                        float p = (kg0 + r > qg) ? 0.f
                                  : __builtin_amdgcn_exp2f(st[mt][ct][r]);
                        lp += p; pk[r] = (bf16)p;
                    }
                    *(bf16x4*)&Ps[pb + ((((ct * 2 + c16base) ^ l8) << 3) + psub)] = pk;
                }
            }
            lsum[mt] += lp;
        }
        // Ps rows wave-private: no barrier

        // O += P @ V   (A = Ps b128 swizzled, B = Vt)
#pragma unroll
        for (int ks = 0; ks < 2; ++ks) {
            bf16x8 bfr[4], afr[2];
#pragma unroll
            for (int ct = 0; ct < 4; ++ct)
                bfr[ct] = *(const bf16x8*)&Vt[(ct * 16 + l16) * 64 + (((ks * 4 + quad) ^ l8) << 3)];
#pragma unroll
            for (int mt = 0; mt < 2; ++mt)
                afr[mt] = *(const bf16x8*)&Ps[(wave * 32 + mt * 16 + l16) * 64 + (((ks * 4 + quad) ^ l8) << 3)];
#pragma unroll
            for (int mt = 0; mt < 2; ++mt)
#pragma unroll
                for (int ct = 0; ct < 4; ++ct)
                    o[mt][ct] = MFMA16(afr[mt], bfr[ct], o[mt][ct]);
        }

        if (j + 1 < jend) {
            __syncthreads();   // all waves done with Vt/Ks[cur]; drains prefetch vmcnt
            writeV(vr);
            __syncthreads();   // Vt(j+1) visible
        }
    }

    // epilogue: lane's lsum covers its quad's 16 k per q=l16; reduce over quads
    float* Op = Opart + (size_t)(h * PARTS_PER_HEAD + idx) * 128 * 64;
    float* Lp = Lpart + (size_t)(h * PARTS_PER_HEAD + idx) * 128;
#pragma unroll
    for (int mt = 0; mt < 2; ++mt) {
        float l = lsum[mt];
        l += __shfl_xor(l, 16);
        l += __shfl_xor(l, 32);                  // full l for q = subtile + l16
        if (lane < 16) Lp[wave * 32 + mt * 16 + l16] = l;
#pragma unroll
        for (int r = 0; r < 4; ++r) {
            const int rl = wave * 32 + mt * 16 + quad * 4 + r;
#pragma unroll
            for (int ct = 0; ct < 4; ++ct)
                Op[rl * 64 + ct * 16 + l16] = o[mt][ct][r];
        }
    }
}

// ---------------------------------------------------------------------------
// combine: X = (sum of partial O) / (sum of partial l), bf16
// ---------------------------------------------------------------------------
__global__ __launch_bounds__(256) void attn_combine_kernel(
    const float* __restrict__ Opart, const float* __restrict__ Lpart,
    bf16* __restrict__ X)
{
    const int qb = blockIdx.x, h = blockIdx.y;
    const int nc = 1 + (qb >> 3);
    const int base = (qb < 8) ? qb
                   : (qb < 16) ? 8 + (qb - 8) * 2
                   : (qb < 24) ? 24 + (qb - 16) * 3
                   : 48 + (qb - 24) * 4;
    const float* Op0 = Opart + (size_t)(h * PARTS_PER_HEAD + base) * 128 * 64;
    const float* Lp0 = Lpart + (size_t)(h * PARTS_PER_HEAD + base) * 128;

    for (int e = threadIdx.x * 4; e < 128 * 64; e += 1024) {
        const int row = e >> 6, col = e & 63;
        float4 acc = {0.f, 0.f, 0.f, 0.f};
        float l = 0.f;
        for (int p = 0; p < nc; ++p) {
            float4 w = *(const float4*)&Op0[p * 128 * 64 + e];
            acc.x += w.x; acc.y += w.y; acc.z += w.z; acc.w += w.w;
            l += Lp0[p * 128 + row];
        }
        const float rl = 1.0f / l;
        bf16x4 ov;
        ov[0] = (bf16)(acc.x * rl); ov[1] = (bf16)(acc.y * rl);
        ov[2] = (bf16)(acc.z * rl); ov[3] = (bf16)(acc.w * rl);
        *(bf16x4*)&X[(size_t)(qb * 128 + row) * DM + h * 64 + col] = ov;
    }
}

// ---------------------------------------------------------------------------
extern "C" void kernel_launch(void* const* d_in, const int* in_sizes, int n_in,
                              void* d_out, int out_size, void* d_ws, size_t ws_size,
                              hipStream_t stream)
{
    const float* q  = (const float*)d_in[0];
    const float* k  = (const float*)d_in[1];
    const float* v  = (const float*)d_in[2];
    // d_in[3] = causal mask, handled analytically
    const float* Wq = (const float*)d_in[4];
    const float* bq = (const float*)d_in[5];
    const float* Wk = (const float*)d_in[6];
    const float* bk = (const float*)d_in[7];
    const float* Wv = (const float*)d_in[8];
    const float* bv = (const float*)d_in[9];
    const float* Wo = (const float*)d_in[10];
    const float* bo = (const float*)d_in[11];

    const size_t NE = (size_t)S_LEN * DM;
    bf16* base = (bf16*)d_ws;
    bf16* Qc = base;
    bf16* Kc = base + NE;
    bf16* Vc = base + 2 * NE;
    bf16* Qp = base + 3 * NE;
    bf16* Kp = base + 4 * NE;
    bf16* Vp = base + 5 * NE;
    bf16* Wt = base + 6 * NE;
    bf16 *Wqt = Wt, *Wkt = Wt + W_ELEMS, *Wvt = Wt + 2 * W_ELEMS, *Wot = Wt + 3 * W_ELEMS;
    float* Opart = (float*)(Wt + 4 * W_ELEMS);
    float* Lpart = Opart + (size_t)NH * PARTS_PER_HEAD * 128 * 64;
    bf16* Xb = Qc;   // Qc dead after projections

    prep_kernel<<<dim3(3072, 4), 256, 0, stream>>>(
        q, k, v, Wq, Wk, Wv, Wo, Qc, Kc, Vc, Wqt, Wkt, Wvt, Wot, (int)NE);
    gemm128_kernel<false><<<dim3(32, 6, 3), 256, 0, stream>>>(
        Qc, Kc, Vc, Wqt, Wkt, Wvt, bq, bk, bv, Qp, Kp, Vp, S_LEN, DM, DM, CE);
    attn_kernel<<<dim3(PARTS_PER_HEAD, NH), 256, 0, stream>>>(Qp, Kp, Vp, Opart, Lpart);
    attn_combine_kernel<<<dim3(32, NH), 256, 0, stream>>>(Opart, Lpart, Xb);
    gemm128_kernel<true><<<dim3(32, 6, 1), 256, 0, stream>>>(
        Xb, Xb, Xb, Wot, Wot, Wot, bo, bo, bo, d_out, d_out, d_out, S_LEN, DM, DM, 1.0f);
}